// Round 10
// baseline (1325.777 us; speedup 1.0000x reference)
//
#include <hip/hip_runtime.h>

#define HID 128
#define NN  100000
#define EE  1600000
#define BB  512
#define LL  4

typedef __attribute__((ext_vector_type(8))) short bf16x8;
typedef __attribute__((ext_vector_type(4))) float f32x4;

__device__ __forceinline__ unsigned short f32_to_bf16(float f) {
    union { float f; unsigned u; } c; c.f = f;
    unsigned r = c.u + 0x7FFFu + ((c.u >> 16) & 1u);
    return (unsigned short)(r >> 16);
}
__device__ __forceinline__ float bf16_to_f32(unsigned short h) {
    union { unsigned u; float f; } c; c.u = ((unsigned)h) << 16; return c.f;
}

// ============================ CSR build ====================================
__global__ __launch_bounds__(256) void hist_kernel(
    const int* __restrict__ ei, int* __restrict__ R)
{
    int e = blockIdx.x * 256 + threadIdx.x;
    if (e >= EE) return;
    atomicAdd(&R[ei[EE + e] + 1], 1);
}

__global__ __launch_bounds__(256) void scan1_kernel(int* __restrict__ R,
                                                    int* __restrict__ aux, int n)
{
    __shared__ int sh[256];
    int base = blockIdx.x * 1024;
    int t = threadIdx.x;
    int v[4]; int s = 0;
#pragma unroll
    for (int i = 0; i < 4; ++i) {
        int idx = base + t * 4 + i;
        v[i] = (idx < n) ? R[idx] : 0;
        s += v[i];
    }
    sh[t] = s; __syncthreads();
#pragma unroll
    for (int off = 1; off < 256; off <<= 1) {
        int val = (t >= off) ? sh[t - off] : 0;
        __syncthreads();
        sh[t] += val;
        __syncthreads();
    }
    int run = (t == 0) ? 0 : sh[t - 1];
#pragma unroll
    for (int i = 0; i < 4; ++i) {
        int idx = base + t * 4 + i;
        run += v[i];
        if (idx < n) R[idx] = run;
    }
    if (t == 255) aux[blockIdx.x] = sh[255];
}

__global__ __launch_bounds__(128) void scan2_kernel(int* __restrict__ aux, int nb)
{
    __shared__ int sh[128];
    int t = threadIdx.x;
    sh[t] = (t < nb) ? aux[t] : 0;
    __syncthreads();
#pragma unroll
    for (int off = 1; off < 128; off <<= 1) {
        int val = (t >= off) ? sh[t - off] : 0;
        __syncthreads();
        sh[t] += val;
        __syncthreads();
    }
    if (t < nb) aux[t] = sh[t];
}

__global__ __launch_bounds__(256) void scan3_kernel(int* __restrict__ R,
                                                    const int* __restrict__ aux, int n)
{
    int b = blockIdx.x + 1;
    int add = aux[b - 1];
#pragma unroll
    for (int i = 0; i < 4; ++i) {
        int idx = b * 1024 + threadIdx.x * 4 + i;
        if (idx < n) R[idx] += add;
    }
}

// fill with PACKED records: src(17b) | a0(5b) | a1(5b) | a2(5b)
__global__ __launch_bounds__(256) void fill_kernel(
    const int* __restrict__ ei, const int* __restrict__ ea,
    int* __restrict__ R, unsigned int* __restrict__ csr)
{
    int e = blockIdx.x * 256 + threadIdx.x;
    if (e >= EE) return;
    int pos = atomicAdd(&R[ei[EE + e]], 1);
    unsigned int rec = (unsigned int)ei[e]
                     | ((unsigned int)ea[e * 3 + 0] << 17)
                     | ((unsigned int)ea[e * 3 + 1] << 22)
                     | ((unsigned int)ea[e * 3 + 2] << 27);
    csr[pos] = rec;
}

// ============================ embedding ====================================
__global__ __launch_bounds__(256) void embed_kernel(
    const int* __restrict__ x_idx, const float* __restrict__ node_emb,
    float* __restrict__ x)
{
    int t = blockIdx.x * 256 + threadIdx.x;
    int node = t >> 5, j = t & 31;
    if (node >= NN) return;
    ((float4*)x)[node * 32 + j] =
        ((const float4*)node_emb)[x_idx[node] * 32 + j];
}

// ====================== gather aggregation (CSR) ===========================
// One wave per node; 2 edges concurrent (32 lanes x float4), unroll x4.
// e1/e2/e3 (31.5 KB total) stay L1-resident: 3 of the 4 loads/edge are L1 hits.
// (R9 lesson: a 4.7 MB precomputed bond table regressed — misses per-XCD L2.)
__device__ __forceinline__ float4 edge_term(
    unsigned int rec, int l32, const float* __restrict__ x,
    const float* __restrict__ e1, const float* __restrict__ e2,
    const float* __restrict__ e3)
{
    int src = rec & 0x1FFFF;
    int i0 = (rec >> 17) & 31, i1 = (rec >> 22) & 31, i2 = (rec >> 27) & 31;
    float4 v  = ((const float4*)x )[src * 32 + l32];
    float4 w1 = ((const float4*)e1)[i0  * 32 + l32];
    float4 w2 = ((const float4*)e2)[i1  * 32 + l32];
    float4 w3 = ((const float4*)e3)[i2  * 32 + l32];
    float4 r;
    r.x = fmaxf(v.x + w1.x + w2.x + w3.x, 0.f);
    r.y = fmaxf(v.y + w1.y + w2.y + w3.y, 0.f);
    r.z = fmaxf(v.z + w1.z + w2.z + w3.z, 0.f);
    r.w = fmaxf(v.w + w1.w + w2.w + w3.w, 0.f);
    return r;
}

// launch_bounds(256, 8): request 8 waves/SIMD (32 waves/CU) residency;
// VGPR cap 64 >= the 36 we use. Gather is latency-bound at 65% occupancy.
__global__ __launch_bounds__(256, 8) void gather_kernel(
    const float* __restrict__ x,
    const float* __restrict__ e1, const float* __restrict__ e2,
    const float* __restrict__ e3,
    const int* __restrict__ rowend, const unsigned int* __restrict__ csr,
    float* __restrict__ agg)
{
    int wid  = (blockIdx.x * 256 + threadIdx.x) >> 6;
    int lane = threadIdx.x & 63;
    int half = lane >> 5;
    int l32  = lane & 31;
    if (wid >= NN) return;
    int beg = (wid == 0) ? 0 : rowend[wid - 1];
    int end = rowend[wid];

    float4 a0 = make_float4(0.f, 0.f, 0.f, 0.f);
    float4 a1 = make_float4(0.f, 0.f, 0.f, 0.f);
    float4 a2 = make_float4(0.f, 0.f, 0.f, 0.f);
    float4 a3 = make_float4(0.f, 0.f, 0.f, 0.f);
    int p = beg + half;
    for (; p + 6 < end; p += 8) {
        unsigned int r0 = csr[p];
        unsigned int r1 = csr[p + 2];
        unsigned int r2 = csr[p + 4];
        unsigned int r3 = csr[p + 6];
        float4 t0 = edge_term(r0, l32, x, e1, e2, e3);
        float4 t1 = edge_term(r1, l32, x, e1, e2, e3);
        float4 t2 = edge_term(r2, l32, x, e1, e2, e3);
        float4 t3 = edge_term(r3, l32, x, e1, e2, e3);
        a0.x += t0.x; a0.y += t0.y; a0.z += t0.z; a0.w += t0.w;
        a1.x += t1.x; a1.y += t1.y; a1.z += t1.z; a1.w += t1.w;
        a2.x += t2.x; a2.y += t2.y; a2.z += t2.z; a2.w += t2.w;
        a3.x += t3.x; a3.y += t3.y; a3.z += t3.z; a3.w += t3.w;
    }
    for (; p < end; p += 2) {
        float4 t0 = edge_term(csr[p], l32, x, e1, e2, e3);
        a0.x += t0.x; a0.y += t0.y; a0.z += t0.z; a0.w += t0.w;
    }
    float4 acc;
    acc.x = (a0.x + a1.x) + (a2.x + a3.x);
    acc.y = (a0.y + a1.y) + (a2.y + a3.y);
    acc.z = (a0.z + a1.z) + (a2.z + a3.z);
    acc.w = (a0.w + a1.w) + (a2.w + a3.w);
    acc.x += __shfl_xor(acc.x, 32);
    acc.y += __shfl_xor(acc.y, 32);
    acc.z += __shfl_xor(acc.z, 32);
    acc.w += __shfl_xor(acc.w, 32);
    if (half == 0)
        ((float4*)agg)[wid * 32 + l32] = acc;
}

// ================= W prep: split f32 -> bf16 hi/lo, swizzle ================
__global__ __launch_bounds__(256) void wprep_kernel(
    const float* __restrict__ W1, const float* __restrict__ W2,
    unsigned short* __restrict__ wf)
{
    int t = blockIdx.x * 256 + threadIdx.x;
    if (t >= LL * 2 * 16384) return;
    int layer = t >> 15;
    int rem = t & 32767;
    int mat = rem >> 14;
    int idx = rem & 16383;
    int k = idx >> 7, n = idx & 127;
    const float* W = (mat ? W2 : W1) + layer * 16384;
    float w = W[k * 128 + n];
    unsigned short hi = f32_to_bf16(w);
    unsigned short lo = f32_to_bf16(w - bf16_to_f32(hi));
    int nb = n >> 4, nl = n & 15, kstep = k >> 5, quad = (k >> 3) & 3, j = k & 7;
    int di = ((nb * 4 + kstep) * 64 + (quad * 16 + nl)) * 8 + j;
    unsigned short* base = wf + (size_t)((layer * 2 + mat) * 2) * 16384;
    base[di] = hi;
    base[16384 + di] = lo;
}

// =================== fallback atomic edge scatter ==========================
__global__ __launch_bounds__(256) void edge_kernel(
    const float* __restrict__ x, const int* __restrict__ ei,
    const int* __restrict__ ea, const float* __restrict__ e1,
    const float* __restrict__ e2, const float* __restrict__ e3,
    float* __restrict__ agg)
{
    int t = blockIdx.x * 256 + threadIdx.x;
    int e = t >> 5, j = t & 31;
    if (e >= EE) return;
    int src = ei[e];
    int dst = ei[EE + e];
    int a0 = ea[e * 3 + 0], a1 = ea[e * 3 + 1], a2 = ea[e * 3 + 2];
    float4 v  = ((const float4*)x )[src * 32 + j];
    float4 w1 = ((const float4*)e1)[a0  * 32 + j];
    float4 w2 = ((const float4*)e2)[a1  * 32 + j];
    float4 w3 = ((const float4*)e3)[a2  * 32 + j];
    float mx = fmaxf(v.x + w1.x + w2.x + w3.x, 0.f);
    float my = fmaxf(v.y + w1.y + w2.y + w3.y, 0.f);
    float mz = fmaxf(v.z + w1.z + w2.z + w3.z, 0.f);
    float mw = fmaxf(v.w + w1.w + w2.w + w3.w, 0.f);
    float* ag = agg + (size_t)dst * HID + j * 4;
    atomicAdd(ag + 0, mx);
    atomicAdd(ag + 1, my);
    atomicAdd(ag + 2, mz);
    atomicAdd(ag + 3, mw);
}

// ==================== fused layer MLP via split-bf16 MFMA ==================
#define TPAD 136
#define UPAD 132

__global__ __launch_bounds__(256) void mlp_mfma_kernel(
    const float* __restrict__ xin, const float* __restrict__ agg,
    const unsigned short* __restrict__ wf,
    const float* __restrict__ b1, const float* __restrict__ b2,
    const float* __restrict__ gamma, const float* __restrict__ beta,
    float* __restrict__ x)
{
    __shared__ __align__(16) char smemA[17408];
    __shared__ __align__(16) unsigned short t_hi[32 * TPAD];
    __shared__ __align__(16) unsigned short t_lo[32 * TPAD];
    unsigned short* h_hi = (unsigned short*)smemA;
    unsigned short* h_lo = (unsigned short*)(smemA + 8704);
    float* u_s = (float*)smemA;

    int tid = threadIdx.x;
    int rbase = blockIdx.x * 32;

    for (int idx = tid; idx < 32 * 32; idx += 256) {
        int r = idx >> 5, c4 = idx & 31;
        float4 xv = ((const float4*)xin)[(rbase + r) * 32 + c4];
        float4 av = ((const float4*)agg)[(rbase + r) * 32 + c4];
        float h0 = xv.x + av.x, h1 = xv.y + av.y;
        float h2 = xv.z + av.z, h3 = xv.w + av.w;
        unsigned short i0 = f32_to_bf16(h0), i1 = f32_to_bf16(h1);
        unsigned short i2 = f32_to_bf16(h2), i3 = f32_to_bf16(h3);
        ushort4 vh = make_ushort4(i0, i1, i2, i3);
        ushort4 vl = make_ushort4(f32_to_bf16(h0 - bf16_to_f32(i0)),
                                  f32_to_bf16(h1 - bf16_to_f32(i1)),
                                  f32_to_bf16(h2 - bf16_to_f32(i2)),
                                  f32_to_bf16(h3 - bf16_to_f32(i3)));
        int o = r * TPAD + c4 * 4;
        *(ushort4*)&h_hi[o] = vh;
        *(ushort4*)&h_lo[o] = vl;
    }
    __syncthreads();

    int lane = tid & 63;
    int wave = tid >> 6;
    int rb   = wave & 1;
    int cbg  = (wave >> 1) * 4;
    int quad = lane >> 4, nl = lane & 15;
    int arow = rb * 16 + nl;

    const unsigned short* w1_hi = wf;
    const unsigned short* w1_lo = wf + 16384;
    const unsigned short* w2_hi = wf + 32768;
    const unsigned short* w2_lo = wf + 49152;

    {
        f32x4 acc[4] = {};
#pragma unroll
        for (int ks = 0; ks < 4; ++ks) {
            int koff = ks * 32 + quad * 8;
            bf16x8 a_hi = *(const bf16x8*)&h_hi[arow * TPAD + koff];
            bf16x8 a_lo = *(const bf16x8*)&h_lo[arow * TPAD + koff];
#pragma unroll
            for (int cb = 0; cb < 4; ++cb) {
                int off = (((cbg + cb) * 4 + ks) * 64 + lane) * 8;
                bf16x8 b_hi = *(const bf16x8*)&w1_hi[off];
                bf16x8 b_lo = *(const bf16x8*)&w1_lo[off];
                acc[cb] = __builtin_amdgcn_mfma_f32_16x16x32_bf16(a_hi, b_hi, acc[cb], 0, 0, 0);
                acc[cb] = __builtin_amdgcn_mfma_f32_16x16x32_bf16(a_lo, b_hi, acc[cb], 0, 0, 0);
                acc[cb] = __builtin_amdgcn_mfma_f32_16x16x32_bf16(a_hi, b_lo, acc[cb], 0, 0, 0);
            }
        }
#pragma unroll
        for (int cb = 0; cb < 4; ++cb) {
            int col = (cbg + cb) * 16 + nl;
            float bv = b1[col];
#pragma unroll
            for (int r = 0; r < 4; ++r) {
                int row = rb * 16 + quad * 4 + r;
                float v = fmaxf(acc[cb][r] + bv, 0.f);
                unsigned short hi = f32_to_bf16(v);
                t_hi[row * TPAD + col] = hi;
                t_lo[row * TPAD + col] = f32_to_bf16(v - bf16_to_f32(hi));
            }
        }
    }
    __syncthreads();

    {
        f32x4 acc[4] = {};
#pragma unroll
        for (int ks = 0; ks < 4; ++ks) {
            int koff = ks * 32 + quad * 8;
            bf16x8 a_hi = *(const bf16x8*)&t_hi[arow * TPAD + koff];
            bf16x8 a_lo = *(const bf16x8*)&t_lo[arow * TPAD + koff];
#pragma unroll
            for (int cb = 0; cb < 4; ++cb) {
                int off = (((cbg + cb) * 4 + ks) * 64 + lane) * 8;
                bf16x8 b_hi = *(const bf16x8*)&w2_hi[off];
                bf16x8 b_lo = *(const bf16x8*)&w2_lo[off];
                acc[cb] = __builtin_amdgcn_mfma_f32_16x16x32_bf16(a_hi, b_hi, acc[cb], 0, 0, 0);
                acc[cb] = __builtin_amdgcn_mfma_f32_16x16x32_bf16(a_lo, b_hi, acc[cb], 0, 0, 0);
                acc[cb] = __builtin_amdgcn_mfma_f32_16x16x32_bf16(a_hi, b_lo, acc[cb], 0, 0, 0);
            }
        }
#pragma unroll
        for (int cb = 0; cb < 4; ++cb) {
            int col = (cbg + cb) * 16 + nl;
            float bv = b2[col];
#pragma unroll
            for (int r = 0; r < 4; ++r) {
                int row = rb * 16 + quad * 4 + r;
                u_s[row * UPAD + col] = acc[cb][r] + bv;
            }
        }
    }
    __syncthreads();

    {
        int tc = tid & 31, tr = tid >> 5;
        float4 gv  = ((const float4*)gamma)[tc];
        float4 btv = ((const float4*)beta )[tc];
#pragma unroll
        for (int j = 0; j < 4; ++j) {
            float4 u4 = *(const float4*)&u_s[(tr * 4 + j) * UPAD + tc * 4];
            float s = u4.x + u4.y + u4.z + u4.w;
            float q = u4.x*u4.x + u4.y*u4.y + u4.z*u4.z + u4.w*u4.w;
#pragma unroll
            for (int off = 1; off < 32; off <<= 1) {
                s += __shfl_xor(s, off, 64);
                q += __shfl_xor(q, off, 64);
            }
            float m   = s * (1.f / 128.f);
            float var = q * (1.f / 128.f) - m * m;
            float rs  = rsqrtf(var + 1e-5f);
            int r = rbase + tr * 4 + j;
            float4 xo = ((float4*)x)[r * 32 + tc];
            float4 o;
            o.x = xo.x + fmaxf((u4.x - m) * rs * gv.x + btv.x, 0.f);
            o.y = xo.y + fmaxf((u4.y - m) * rs * gv.y + btv.y, 0.f);
            o.z = xo.z + fmaxf((u4.z - m) * rs * gv.z + btv.z, 0.f);
            o.w = xo.w + fmaxf((u4.w - m) * rs * gv.w + btv.w, 0.f);
            ((float4*)x)[r * 32 + tc] = o;
        }
    }
}

// ============== fallback split GEMMs (non-fast path only) ==================
__global__ __launch_bounds__(256) void gemm_relu_kernel(
    const float* __restrict__ x, const float* __restrict__ agg,
    const float* __restrict__ W, const float* __restrict__ bias,
    float* __restrict__ t)
{
    __shared__ float h_s[32 * 129];
    int tid = threadIdx.x;
    int tc = tid & 31, tr = tid >> 5;
    int rbase = blockIdx.x * 32;
    for (int idx = tid; idx < 32 * 128; idx += 256) {
        int r = idx >> 7, k = idx & 127;
        int g = (rbase + r) * HID + k;
        h_s[r * 129 + k] = x[g] + agg[g];
    }
    __syncthreads();
    float acc[4][4] = {};
    const float4* W4 = (const float4*)W;
#pragma unroll 4
    for (int k = 0; k < 128; ++k) {
        float4 w = W4[k * 32 + tc];
#pragma unroll
        for (int j = 0; j < 4; ++j) {
            float hv = h_s[(tr * 4 + j) * 129 + k];
            acc[j][0] = fmaf(hv, w.x, acc[j][0]);
            acc[j][1] = fmaf(hv, w.y, acc[j][1]);
            acc[j][2] = fmaf(hv, w.z, acc[j][2]);
            acc[j][3] = fmaf(hv, w.w, acc[j][3]);
        }
    }
    float4 bv = ((const float4*)bias)[tc];
#pragma unroll
    for (int j = 0; j < 4; ++j) {
        int r = rbase + tr * 4 + j;
        float4 o;
        o.x = fmaxf(acc[j][0] + bv.x, 0.f);
        o.y = fmaxf(acc[j][1] + bv.y, 0.f);
        o.z = fmaxf(acc[j][2] + bv.z, 0.f);
        o.w = fmaxf(acc[j][3] + bv.w, 0.f);
        ((float4*)t)[r * 32 + tc] = o;
    }
}

__global__ __launch_bounds__(256) void gemm_ln_res_kernel(
    const float* __restrict__ t, const float* __restrict__ W,
    const float* __restrict__ bias, const float* __restrict__ gamma,
    const float* __restrict__ beta, float* __restrict__ x)
{
    __shared__ float h_s[32 * 129];
    int tid = threadIdx.x;
    int tc = tid & 31, tr = tid >> 5;
    int rbase = blockIdx.x * 32;
    for (int idx = tid; idx < 32 * 128; idx += 256) {
        int r = idx >> 7, k = idx & 127;
        h_s[r * 129 + k] = t[(rbase + r) * HID + k];
    }
    __syncthreads();
    float acc[4][4] = {};
    const float4* W4 = (const float4*)W;
#pragma unroll 4
    for (int k = 0; k < 128; ++k) {
        float4 w = W4[k * 32 + tc];
#pragma unroll
        for (int j = 0; j < 4; ++j) {
            float hv = h_s[(tr * 4 + j) * 129 + k];
            acc[j][0] = fmaf(hv, w.x, acc[j][0]);
            acc[j][1] = fmaf(hv, w.y, acc[j][1]);
            acc[j][2] = fmaf(hv, w.z, acc[j][2]);
            acc[j][3] = fmaf(hv, w.w, acc[j][3]);
        }
    }
    float4 bv  = ((const float4*)bias )[tc];
    float4 gv  = ((const float4*)gamma)[tc];
    float4 btv = ((const float4*)beta )[tc];
#pragma unroll
    for (int j = 0; j < 4; ++j) {
        acc[j][0] += bv.x; acc[j][1] += bv.y;
        acc[j][2] += bv.z; acc[j][3] += bv.w;
        float s = acc[j][0] + acc[j][1] + acc[j][2] + acc[j][3];
        float q = acc[j][0]*acc[j][0] + acc[j][1]*acc[j][1]
                + acc[j][2]*acc[j][2] + acc[j][3]*acc[j][3];
#pragma unroll
        for (int off = 1; off < 32; off <<= 1) {
            s += __shfl_xor(s, off, 64);
            q += __shfl_xor(q, off, 64);
        }
        float m   = s * (1.f / 128.f);
        float var = q * (1.f / 128.f) - m * m;
        float rs  = rsqrtf(var + 1e-5f);
        int r = rbase + tr * 4 + j;
        float4 xo = ((float4*)x)[r * 32 + tc];
        float4 o;
        o.x = xo.x + fmaxf((acc[j][0] - m) * rs * gv.x + btv.x, 0.f);
        o.y = xo.y + fmaxf((acc[j][1] - m) * rs * gv.y + btv.y, 0.f);
        o.z = xo.z + fmaxf((acc[j][2] - m) * rs * gv.z + btv.z, 0.f);
        o.w = xo.w + fmaxf((acc[j][3] - m) * rs * gv.w + btv.w, 0.f);
        ((float4*)x)[r * 32 + tc] = o;
    }
}

// ============================ mean pool ====================================
#define PCHUNK 32
__global__ __launch_bounds__(256) void pool_kernel(
    const float* __restrict__ x, const int* __restrict__ batch,
    float* __restrict__ sums, int* __restrict__ cnt)
{
    int wave = (blockIdx.x * 256 + threadIdx.x) >> 6;
    int lane = threadIdx.x & 63;
    int n0 = wave * PCHUNK;
    if (n0 >= NN) return;
    int n1 = n0 + PCHUNK; if (n1 > NN) n1 = NN;

    float2 acc = make_float2(0.f, 0.f);
    int cur = batch[n0];
    int run = 0;
    for (int n = n0; n < n1; ++n) {
        int b = batch[n];
        if (b != cur) {
            float* sp = sums + cur * HID + lane * 2;
            atomicAdd(sp + 0, acc.x);
            atomicAdd(sp + 1, acc.y);
            if (lane == 0) atomicAdd(&cnt[cur], run);
            acc = make_float2(0.f, 0.f);
            run = 0; cur = b;
        }
        float2 v = ((const float2*)x)[(size_t)n * 64 + lane];
        acc.x += v.x; acc.y += v.y; ++run;
    }
    float* sp = sums + cur * HID + lane * 2;
    atomicAdd(sp + 0, acc.x);
    atomicAdd(sp + 1, acc.y);
    if (lane == 0) atomicAdd(&cnt[cur], run);
}

// ============================ head =========================================
__global__ __launch_bounds__(128) void head_kernel(
    const float* __restrict__ sums, const int* __restrict__ cnt,
    const float* __restrict__ pW1, const float* __restrict__ pb1,
    const float* __restrict__ pW2, const float* __restrict__ pb2,
    const float* __restrict__ pg, const float* __restrict__ pbn,
    const float* __restrict__ oW, const float* __restrict__ ob,
    float* __restrict__ out)
{
    __shared__ float s0[128], s1[128], red[4];
    int b = blockIdx.x, c = threadIdx.x;

    float cn = fmaxf((float)cnt[b], 1.f);
    s0[c] = sums[b * HID + c] / cn;
    __syncthreads();

    float a = pb1[c];
#pragma unroll 4
    for (int k = 0; k < HID; ++k) a = fmaf(s0[k], pW1[k * HID + c], a);
    a = fmaxf(a, 0.f);
    s1[c] = a;
    __syncthreads();

    float u = pb2[c];
#pragma unroll 4
    for (int k = 0; k < HID; ++k) u = fmaf(s1[k], pW2[k * HID + c], u);

    float s = u, q = u * u;
#pragma unroll
    for (int off = 1; off < 64; off <<= 1) {
        s += __shfl_xor(s, off, 64);
        q += __shfl_xor(q, off, 64);
    }
    if ((c & 63) == 0) { red[(c >> 6) * 2] = s; red[(c >> 6) * 2 + 1] = q; }
    __syncthreads();
    float S = red[0] + red[2], Q = red[1] + red[3];
    float m = S * (1.f / 128.f);
    float var = Q * (1.f / 128.f) - m * m;
    float rs = rsqrtf(var + 1e-5f);
    float v = fmaxf((u - m) * rs * pg[c] + pbn[c], 0.f);

    float p = v * oW[c];
#pragma unroll
    for (int off = 1; off < 64; off <<= 1) p += __shfl_xor(p, off, 64);
    __syncthreads();
    if ((c & 63) == 0) red[c >> 6] = p;
    __syncthreads();
    if (c == 0) {
        float tot = red[0] + red[1] + ob[0];
        out[b] = 1.f / (1.f + expf(-tot));
    }
}

// ===========================================================================
extern "C" void kernel_launch(void* const* d_in, const int* in_sizes, int n_in,
                              void* d_out, int out_size, void* d_ws, size_t ws_size,
                              hipStream_t stream)
{
    const int*   x_idx    = (const int*)d_in[0];
    const int*   ei       = (const int*)d_in[1];
    const int*   ea       = (const int*)d_in[2];
    const int*   batch    = (const int*)d_in[3];
    const float* node_emb = (const float*)d_in[4];
    const float* e1       = (const float*)d_in[5];
    const float* e2       = (const float*)d_in[6];
    const float* e3       = (const float*)d_in[7];
    const float* W1       = (const float*)d_in[8];
    const float* b1       = (const float*)d_in[9];
    const float* W2       = (const float*)d_in[10];
    const float* b2       = (const float*)d_in[11];
    const float* lg       = (const float*)d_in[12];
    const float* lb       = (const float*)d_in[13];
    const float* pW1      = (const float*)d_in[14];
    const float* pb1      = (const float*)d_in[15];
    const float* pW2      = (const float*)d_in[16];
    const float* pb2      = (const float*)d_in[17];
    const float* pg       = (const float*)d_in[18];
    const float* pbn      = (const float*)d_in[19];
    const float* oW       = (const float*)d_in[20];
    const float* ob       = (const float*)d_in[21];
    float* out = (float*)d_out;

    char* base = (char*)d_ws;
    size_t Sx = (size_t)NN * HID * sizeof(float);           // 51.2 MB
    float* x    = (float*)(base);
    float* agg  = (float*)(base + Sx);
    float* sums = (float*)(base + 2 * Sx);
    int*   cnt  = (int*)  (base + 2 * Sx + BB * HID * 4);
    int*   R    = (int*)  (base + 2 * Sx + BB * HID * 4 + 2048);
    unsigned int* csr = (unsigned int*)((char*)R + 400016);
    int*   aux  = (int*)  ((char*)csr + (size_t)EE * 4);
    unsigned short* wf = (unsigned short*)((char*)aux + 512);
    size_t need = ((char*)wf + (size_t)LL * 2 * 2 * 16384 * 2) - base;

    bool fast = (ws_size >= need);

    embed_kernel<<<(NN * 32 + 255) / 256, 256, 0, stream>>>(x_idx, node_emb, x);

    if (fast) {
        const int n = NN + 1, NB = (n + 1023) / 1024;
        hipMemsetAsync(R, 0, (size_t)n * sizeof(int), stream);
        hist_kernel <<<(EE + 255) / 256, 256, 0, stream>>>(ei, R);
        scan1_kernel<<<NB, 256, 0, stream>>>(R, aux, n);
        scan2_kernel<<<1, 128, 0, stream>>>(aux, NB);
        scan3_kernel<<<NB - 1, 256, 0, stream>>>(R, aux, n);
        fill_kernel <<<(EE + 255) / 256, 256, 0, stream>>>(ei, ea, R, csr);
        wprep_kernel<<<(LL * 2 * 16384 + 255) / 256, 256, 0, stream>>>(W1, W2, wf);
    }

    for (int l = 0; l < LL; ++l) {
        if (fast) {
            gather_kernel<<<(NN * 64 + 255) / 256, 256, 0, stream>>>(
                x, e1, e2, e3, R, csr, agg);
            mlp_mfma_kernel<<<NN / 32, 256, 0, stream>>>(
                x, agg, wf + (size_t)l * 65536,
                b1 + l * HID, b2 + l * HID,
                lg + l * HID, lb + l * HID, x);
        } else {
            hipMemsetAsync(agg, 0, Sx, stream);
            edge_kernel<<<(EE * 32 + 255) / 256, 256, 0, stream>>>(
                x, ei, ea, e1, e2, e3, agg);
            gemm_relu_kernel<<<NN / 32, 256, 0, stream>>>(
                x, agg, W1 + l * HID * HID, b1 + l * HID, agg);
            gemm_ln_res_kernel<<<NN / 32, 256, 0, stream>>>(
                agg, W2 + l * HID * HID, b2 + l * HID,
                lg + l * HID, lb + l * HID, x);
        }
    }

    hipMemsetAsync(sums, 0,
                   (size_t)BB * HID * sizeof(float) + BB * sizeof(int), stream);
    {
        int waves = (NN + PCHUNK - 1) / PCHUNK;
        int blocks = (waves + 3) / 4;
        pool_kernel<<<blocks, 256, 0, stream>>>(x, batch, sums, cnt);
    }
    head_kernel<<<BB, 128, 0, stream>>>(
        sums, cnt, pW1, pb1, pW2, pb2, pg, pbn, oW, ob, out);
}

// Round 12
// 1085.304 us; speedup vs baseline: 1.2216x; 1.2216x over previous
//
#include <hip/hip_runtime.h>

#define HID 128
#define NN  100000
#define EE  1600000
#define BB  512
#define LL  4
#define FROWS 16          // rows per fused-layer block

typedef __attribute__((ext_vector_type(8))) short bf16x8;
typedef __attribute__((ext_vector_type(4))) float f32x4;

__device__ __forceinline__ unsigned short f32_to_bf16(float f) {
    union { float f; unsigned u; } c; c.f = f;
    unsigned r = c.u + 0x7FFFu + ((c.u >> 16) & 1u);
    return (unsigned short)(r >> 16);
}
__device__ __forceinline__ float bf16_to_f32(unsigned short h) {
    union { unsigned u; float f; } c; c.u = ((unsigned)h) << 16; return c.f;
}

// ============================ CSR build ====================================
__global__ __launch_bounds__(256) void hist_kernel(
    const int* __restrict__ ei, int* __restrict__ R)
{
    int e = blockIdx.x * 256 + threadIdx.x;
    if (e >= EE) return;
    atomicAdd(&R[ei[EE + e] + 1], 1);
}

__global__ __launch_bounds__(256) void scan1_kernel(int* __restrict__ R,
                                                    int* __restrict__ aux, int n)
{
    __shared__ int sh[256];
    int base = blockIdx.x * 1024;
    int t = threadIdx.x;
    int v[4]; int s = 0;
#pragma unroll
    for (int i = 0; i < 4; ++i) {
        int idx = base + t * 4 + i;
        v[i] = (idx < n) ? R[idx] : 0;
        s += v[i];
    }
    sh[t] = s; __syncthreads();
#pragma unroll
    for (int off = 1; off < 256; off <<= 1) {
        int val = (t >= off) ? sh[t - off] : 0;
        __syncthreads();
        sh[t] += val;
        __syncthreads();
    }
    int run = (t == 0) ? 0 : sh[t - 1];
#pragma unroll
    for (int i = 0; i < 4; ++i) {
        int idx = base + t * 4 + i;
        run += v[i];
        if (idx < n) R[idx] = run;
    }
    if (t == 255) aux[blockIdx.x] = sh[255];
}

__global__ __launch_bounds__(128) void scan2_kernel(int* __restrict__ aux, int nb)
{
    __shared__ int sh[128];
    int t = threadIdx.x;
    sh[t] = (t < nb) ? aux[t] : 0;
    __syncthreads();
#pragma unroll
    for (int off = 1; off < 128; off <<= 1) {
        int val = (t >= off) ? sh[t - off] : 0;
        __syncthreads();
        sh[t] += val;
        __syncthreads();
    }
    if (t < nb) aux[t] = sh[t];
}

__global__ __launch_bounds__(256) void scan3_kernel(int* __restrict__ R,
                                                    const int* __restrict__ aux, int n)
{
    int b = blockIdx.x + 1;
    int add = aux[b - 1];
#pragma unroll
    for (int i = 0; i < 4; ++i) {
        int idx = b * 1024 + threadIdx.x * 4 + i;
        if (idx < n) R[idx] += add;
    }
}

// fill with PACKED records: src(17b) | a0(5b) | a1(5b) | a2(5b)
__global__ __launch_bounds__(256) void fill_kernel(
    const int* __restrict__ ei, const int* __restrict__ ea,
    int* __restrict__ R, unsigned int* __restrict__ csr)
{
    int e = blockIdx.x * 256 + threadIdx.x;
    if (e >= EE) return;
    int pos = atomicAdd(&R[ei[EE + e]], 1);
    unsigned int rec = (unsigned int)ei[e]
                     | ((unsigned int)ea[e * 3 + 0] << 17)
                     | ((unsigned int)ea[e * 3 + 1] << 22)
                     | ((unsigned int)ea[e * 3 + 2] << 27);
    csr[pos] = rec;
}

// ============================ embedding ====================================
__global__ __launch_bounds__(256) void embed_kernel(
    const int* __restrict__ x_idx, const float* __restrict__ node_emb,
    float* __restrict__ x)
{
    int t = blockIdx.x * 256 + threadIdx.x;
    int node = t >> 5, j = t & 31;
    if (node >= NN) return;
    ((float4*)x)[node * 32 + j] =
        ((const float4*)node_emb)[x_idx[node] * 32 + j];
}

// ================= W prep: split f32 -> bf16 hi/lo, swizzle ================
__global__ __launch_bounds__(256) void wprep_kernel(
    const float* __restrict__ W1, const float* __restrict__ W2,
    unsigned short* __restrict__ wf)
{
    int t = blockIdx.x * 256 + threadIdx.x;
    if (t >= LL * 2 * 16384) return;
    int layer = t >> 15;
    int rem = t & 32767;
    int mat = rem >> 14;
    int idx = rem & 16383;
    int k = idx >> 7, n = idx & 127;
    const float* W = (mat ? W2 : W1) + layer * 16384;
    float w = W[k * 128 + n];
    unsigned short hi = f32_to_bf16(w);
    unsigned short lo = f32_to_bf16(w - bf16_to_f32(hi));
    int nb = n >> 4, nl = n & 15, kstep = k >> 5, quad = (k >> 3) & 3, j = k & 7;
    int di = ((nb * 4 + kstep) * 64 + (quad * 16 + nl)) * 8 + j;
    unsigned short* base = wf + (size_t)((layer * 2 + mat) * 2) * 16384;
    base[di] = hi;
    base[16384 + di] = lo;
}

// ====================== edge term (f32, R8-proven) =========================
__device__ __forceinline__ float4 edge_term(
    unsigned int rec, int l32, const float* __restrict__ x,
    const float* __restrict__ e1, const float* __restrict__ e2,
    const float* __restrict__ e3)
{
    int src = rec & 0x1FFFF;
    int i0 = (rec >> 17) & 31, i1 = (rec >> 22) & 31, i2 = (rec >> 27) & 31;
    float4 v  = ((const float4*)x )[src * 32 + l32];
    float4 w1 = ((const float4*)e1)[i0  * 32 + l32];
    float4 w2 = ((const float4*)e2)[i1  * 32 + l32];
    float4 w3 = ((const float4*)e3)[i2  * 32 + l32];
    float4 r;
    r.x = fmaxf(v.x + w1.x + w2.x + w3.x, 0.f);
    r.y = fmaxf(v.y + w1.y + w2.y + w3.y, 0.f);
    r.z = fmaxf(v.z + w1.z + w2.z + w3.z, 0.f);
    r.w = fmaxf(v.w + w1.w + w2.w + w3.w, 0.f);
    return r;
}

// =================== FUSED layer: gather + MLP + LN ========================
// Per block: 16 nodes. Phase1: 4 waves gather 4 nodes each (f32 x, R8 loop),
// h = x+agg split hi/lo into LDS. Phase2/3: split-bf16 MFMA GEMMs. Phase4:
// LN + relu + residual, reading xin, writing xout (double-buffered x — the
// gather of other blocks still sees the untouched xin).
#define TPAD 136   // bf16 row stride
#define UPAD 132   // f32 row stride

__global__ __launch_bounds__(256) void layer_fused_kernel(
    const float* __restrict__ xin,
    const float* __restrict__ e1, const float* __restrict__ e2,
    const float* __restrict__ e3,
    const int* __restrict__ rowend, const unsigned int* __restrict__ csr,
    const unsigned short* __restrict__ wf,
    const float* __restrict__ b1, const float* __restrict__ b2,
    const float* __restrict__ gamma, const float* __restrict__ beta,
    float* __restrict__ xout)
{
    // region A: h_hi/h_lo (2 x 4352 B), later aliased by u (8448 B f32)
    __shared__ __align__(16) char smemA[8704];
    __shared__ __align__(16) unsigned short t_hi[FROWS * TPAD];
    __shared__ __align__(16) unsigned short t_lo[FROWS * TPAD];
    unsigned short* h_hi = (unsigned short*)smemA;
    unsigned short* h_lo = (unsigned short*)(smemA + 4352);
    float* u_s = (float*)smemA;

    int tid = threadIdx.x;
    int rbase = blockIdx.x * FROWS;
    int w = tid >> 6;
    int lane = tid & 63;
    int half = lane >> 5;
    int l32  = lane & 31;

    // ---- Phase 1: gather 4 nodes per wave ----
    for (int ln = w * 4; ln < w * 4 + 4; ++ln) {
        int node = rbase + ln;                      // NN % FROWS == 0
        int beg = (node == 0) ? 0 : rowend[node - 1];
        int end = rowend[node];

        float4 a0 = make_float4(0.f, 0.f, 0.f, 0.f);
        float4 a1 = make_float4(0.f, 0.f, 0.f, 0.f);
        float4 a2 = make_float4(0.f, 0.f, 0.f, 0.f);
        float4 a3 = make_float4(0.f, 0.f, 0.f, 0.f);
        int p = beg + half;
        for (; p + 6 < end; p += 8) {
            unsigned int r0 = csr[p];
            unsigned int r1 = csr[p + 2];
            unsigned int r2 = csr[p + 4];
            unsigned int r3 = csr[p + 6];
            float4 t0 = edge_term(r0, l32, xin, e1, e2, e3);
            float4 t1 = edge_term(r1, l32, xin, e1, e2, e3);
            float4 t2 = edge_term(r2, l32, xin, e1, e2, e3);
            float4 t3 = edge_term(r3, l32, xin, e1, e2, e3);
            a0.x += t0.x; a0.y += t0.y; a0.z += t0.z; a0.w += t0.w;
            a1.x += t1.x; a1.y += t1.y; a1.z += t1.z; a1.w += t1.w;
            a2.x += t2.x; a2.y += t2.y; a2.z += t2.z; a2.w += t2.w;
            a3.x += t3.x; a3.y += t3.y; a3.z += t3.z; a3.w += t3.w;
        }
        for (; p < end; p += 2) {
            float4 t0 = edge_term(csr[p], l32, xin, e1, e2, e3);
            a0.x += t0.x; a0.y += t0.y; a0.z += t0.z; a0.w += t0.w;
        }
        float4 acc;
        acc.x = (a0.x + a1.x) + (a2.x + a3.x);
        acc.y = (a0.y + a1.y) + (a2.y + a3.y);
        acc.z = (a0.z + a1.z) + (a2.z + a3.z);
        acc.w = (a0.w + a1.w) + (a2.w + a3.w);
        acc.x += __shfl_xor(acc.x, 32);
        acc.y += __shfl_xor(acc.y, 32);
        acc.z += __shfl_xor(acc.z, 32);
        acc.w += __shfl_xor(acc.w, 32);
        if (half == 0) {
            float4 xv = ((const float4*)xin)[node * 32 + l32];
            float h0 = xv.x + acc.x, h1 = xv.y + acc.y;
            float h2 = xv.z + acc.z, h3 = xv.w + acc.w;
            unsigned short i0 = f32_to_bf16(h0), i1 = f32_to_bf16(h1);
            unsigned short i2 = f32_to_bf16(h2), i3 = f32_to_bf16(h3);
            int o = ln * TPAD + l32 * 4;
            *(ushort4*)&h_hi[o] = make_ushort4(i0, i1, i2, i3);
            *(ushort4*)&h_lo[o] =
                make_ushort4(f32_to_bf16(h0 - bf16_to_f32(i0)),
                             f32_to_bf16(h1 - bf16_to_f32(i1)),
                             f32_to_bf16(h2 - bf16_to_f32(i2)),
                             f32_to_bf16(h3 - bf16_to_f32(i3)));
        }
    }
    __syncthreads();

    int quad = lane >> 4, nl = lane & 15;
    int cbg = w * 2;                    // 2 col-blocks per wave (8 total)
    const unsigned short* w1_hi = wf;
    const unsigned short* w1_lo = wf + 16384;
    const unsigned short* w2_hi = wf + 32768;
    const unsigned short* w2_lo = wf + 49152;

    // ---- Phase 2: GEMM1  t = relu(h @ W1 + b1) ----
    {
        f32x4 acc[2] = {};
#pragma unroll
        for (int ks = 0; ks < 4; ++ks) {
            int koff = ks * 32 + quad * 8;
            bf16x8 a_hi = *(const bf16x8*)&h_hi[nl * TPAD + koff];
            bf16x8 a_lo = *(const bf16x8*)&h_lo[nl * TPAD + koff];
#pragma unroll
            for (int cb = 0; cb < 2; ++cb) {
                int off = (((cbg + cb) * 4 + ks) * 64 + lane) * 8;
                bf16x8 b_hi = *(const bf16x8*)&w1_hi[off];
                bf16x8 b_lo = *(const bf16x8*)&w1_lo[off];
                acc[cb] = __builtin_amdgcn_mfma_f32_16x16x32_bf16(a_hi, b_hi, acc[cb], 0, 0, 0);
                acc[cb] = __builtin_amdgcn_mfma_f32_16x16x32_bf16(a_lo, b_hi, acc[cb], 0, 0, 0);
                acc[cb] = __builtin_amdgcn_mfma_f32_16x16x32_bf16(a_hi, b_lo, acc[cb], 0, 0, 0);
            }
        }
#pragma unroll
        for (int cb = 0; cb < 2; ++cb) {
            int col = (cbg + cb) * 16 + nl;
            float bv = b1[col];
#pragma unroll
            for (int r = 0; r < 4; ++r) {
                int row = quad * 4 + r;
                float v = fmaxf(acc[cb][r] + bv, 0.f);
                unsigned short hi = f32_to_bf16(v);
                t_hi[row * TPAD + col] = hi;
                t_lo[row * TPAD + col] = f32_to_bf16(v - bf16_to_f32(hi));
            }
        }
    }
    __syncthreads();

    // ---- Phase 3: GEMM2  u = t @ W2 + b2 (u overwrites h region) ----
    {
        f32x4 acc[2] = {};
#pragma unroll
        for (int ks = 0; ks < 4; ++ks) {
            int koff = ks * 32 + quad * 8;
            bf16x8 a_hi = *(const bf16x8*)&t_hi[nl * TPAD + koff];
            bf16x8 a_lo = *(const bf16x8*)&t_lo[nl * TPAD + koff];
#pragma unroll
            for (int cb = 0; cb < 2; ++cb) {
                int off = (((cbg + cb) * 4 + ks) * 64 + lane) * 8;
                bf16x8 b_hi = *(const bf16x8*)&w2_hi[off];
                bf16x8 b_lo = *(const bf16x8*)&w2_lo[off];
                acc[cb] = __builtin_amdgcn_mfma_f32_16x16x32_bf16(a_hi, b_hi, acc[cb], 0, 0, 0);
                acc[cb] = __builtin_amdgcn_mfma_f32_16x16x32_bf16(a_lo, b_hi, acc[cb], 0, 0, 0);
                acc[cb] = __builtin_amdgcn_mfma_f32_16x16x32_bf16(a_hi, b_lo, acc[cb], 0, 0, 0);
            }
        }
#pragma unroll
        for (int cb = 0; cb < 2; ++cb) {
            int col = (cbg + cb) * 16 + nl;
            float bv = b2[col];
#pragma unroll
            for (int r = 0; r < 4; ++r) {
                int row = quad * 4 + r;
                u_s[row * UPAD + col] = acc[cb][r] + bv;
            }
        }
    }
    __syncthreads();

    // ---- Phase 4: LN + relu + residual; xout = xin + relu(LN(u)) ----
    {
        int tc = tid & 31, tr = tid >> 5;      // tr in 0..7, 2 rows each
        float4 gv  = ((const float4*)gamma)[tc];
        float4 btv = ((const float4*)beta )[tc];
#pragma unroll
        for (int j = 0; j < 2; ++j) {
            int row = tr * 2 + j;
            float4 u4 = *(const float4*)&u_s[row * UPAD + tc * 4];
            float s = u4.x + u4.y + u4.z + u4.w;
            float q = u4.x*u4.x + u4.y*u4.y + u4.z*u4.z + u4.w*u4.w;
#pragma unroll
            for (int off = 1; off < 32; off <<= 1) {
                s += __shfl_xor(s, off, 64);
                q += __shfl_xor(q, off, 64);
            }
            float m   = s * (1.f / 128.f);
            float var = q * (1.f / 128.f) - m * m;
            float rs  = rsqrtf(var + 1e-5f);
            int g = rbase + row;
            float4 xo = ((const float4*)xin)[g * 32 + tc];
            float4 o;
            o.x = xo.x + fmaxf((u4.x - m) * rs * gv.x + btv.x, 0.f);
            o.y = xo.y + fmaxf((u4.y - m) * rs * gv.y + btv.y, 0.f);
            o.z = xo.z + fmaxf((u4.z - m) * rs * gv.z + btv.z, 0.f);
            o.w = xo.w + fmaxf((u4.w - m) * rs * gv.w + btv.w, 0.f);
            ((float4*)xout)[g * 32 + tc] = o;
        }
    }
}

// =================== fallback atomic edge scatter ==========================
__global__ __launch_bounds__(256) void edge_kernel(
    const float* __restrict__ x, const int* __restrict__ ei,
    const int* __restrict__ ea, const float* __restrict__ e1,
    const float* __restrict__ e2, const float* __restrict__ e3,
    float* __restrict__ agg)
{
    int t = blockIdx.x * 256 + threadIdx.x;
    int e = t >> 5, j = t & 31;
    if (e >= EE) return;
    int src = ei[e];
    int dst = ei[EE + e];
    int a0 = ea[e * 3 + 0], a1 = ea[e * 3 + 1], a2 = ea[e * 3 + 2];
    float4 v  = ((const float4*)x )[src * 32 + j];
    float4 w1 = ((const float4*)e1)[a0  * 32 + j];
    float4 w2 = ((const float4*)e2)[a1  * 32 + j];
    float4 w3 = ((const float4*)e3)[a2  * 32 + j];
    float mx = fmaxf(v.x + w1.x + w2.x + w3.x, 0.f);
    float my = fmaxf(v.y + w1.y + w2.y + w3.y, 0.f);
    float mz = fmaxf(v.z + w1.z + w2.z + w3.z, 0.f);
    float mw = fmaxf(v.w + w1.w + w2.w + w3.w, 0.f);
    float* ag = agg + (size_t)dst * HID + j * 4;
    atomicAdd(ag + 0, mx);
    atomicAdd(ag + 1, my);
    atomicAdd(ag + 2, mz);
    atomicAdd(ag + 3, mw);
}

// ============== fallback split GEMMs (non-fast path only) ==================
__global__ __launch_bounds__(256) void gemm_relu_kernel(
    const float* __restrict__ x, const float* __restrict__ agg,
    const float* __restrict__ W, const float* __restrict__ bias,
    float* __restrict__ t)
{
    __shared__ float h_s[32 * 129];
    int tid = threadIdx.x;
    int tc = tid & 31, tr = tid >> 5;
    int rbase = blockIdx.x * 32;
    for (int idx = tid; idx < 32 * 128; idx += 256) {
        int r = idx >> 7, k = idx & 127;
        int g = (rbase + r) * HID + k;
        h_s[r * 129 + k] = x[g] + agg[g];
    }
    __syncthreads();
    float acc[4][4] = {};
    const float4* W4 = (const float4*)W;
#pragma unroll 4
    for (int k = 0; k < 128; ++k) {
        float4 w = W4[k * 32 + tc];
#pragma unroll
        for (int j = 0; j < 4; ++j) {
            float hv = h_s[(tr * 4 + j) * 129 + k];
            acc[j][0] = fmaf(hv, w.x, acc[j][0]);
            acc[j][1] = fmaf(hv, w.y, acc[j][1]);
            acc[j][2] = fmaf(hv, w.z, acc[j][2]);
            acc[j][3] = fmaf(hv, w.w, acc[j][3]);
        }
    }
    float4 bv = ((const float4*)bias)[tc];
#pragma unroll
    for (int j = 0; j < 4; ++j) {
        int r = rbase + tr * 4 + j;
        float4 o;
        o.x = fmaxf(acc[j][0] + bv.x, 0.f);
        o.y = fmaxf(acc[j][1] + bv.y, 0.f);
        o.z = fmaxf(acc[j][2] + bv.z, 0.f);
        o.w = fmaxf(acc[j][3] + bv.w, 0.f);
        ((float4*)t)[r * 32 + tc] = o;
    }
}

__global__ __launch_bounds__(256) void gemm_ln_res_kernel(
    const float* __restrict__ t, const float* __restrict__ W,
    const float* __restrict__ bias, const float* __restrict__ gamma,
    const float* __restrict__ beta, float* __restrict__ x)
{
    __shared__ float h_s[32 * 129];
    int tid = threadIdx.x;
    int tc = tid & 31, tr = tid >> 5;
    int rbase = blockIdx.x * 32;
    for (int idx = tid; idx < 32 * 128; idx += 256) {
        int r = idx >> 7, k = idx & 127;
        h_s[r * 129 + k] = t[(rbase + r) * HID + k];
    }
    __syncthreads();
    float acc[4][4] = {};
    const float4* W4 = (const float4*)W;
#pragma unroll 4
    for (int k = 0; k < 128; ++k) {
        float4 w = W4[k * 32 + tc];
#pragma unroll
        for (int j = 0; j < 4; ++j) {
            float hv = h_s[(tr * 4 + j) * 129 + k];
            acc[j][0] = fmaf(hv, w.x, acc[j][0]);
            acc[j][1] = fmaf(hv, w.y, acc[j][1]);
            acc[j][2] = fmaf(hv, w.z, acc[j][2]);
            acc[j][3] = fmaf(hv, w.w, acc[j][3]);
        }
    }
    float4 bv  = ((const float4*)bias )[tc];
    float4 gv  = ((const float4*)gamma)[tc];
    float4 btv = ((const float4*)beta )[tc];
#pragma unroll
    for (int j = 0; j < 4; ++j) {
        acc[j][0] += bv.x; acc[j][1] += bv.y;
        acc[j][2] += bv.z; acc[j][3] += bv.w;
        float s = acc[j][0] + acc[j][1] + acc[j][2] + acc[j][3];
        float q = acc[j][0]*acc[j][0] + acc[j][1]*acc[j][1]
                + acc[j][2]*acc[j][2] + acc[j][3]*acc[j][3];
#pragma unroll
        for (int off = 1; off < 32; off <<= 1) {
            s += __shfl_xor(s, off, 64);
            q += __shfl_xor(q, off, 64);
        }
        float m   = s * (1.f / 128.f);
        float var = q * (1.f / 128.f) - m * m;
        float rs  = rsqrtf(var + 1e-5f);
        int r = rbase + tr * 4 + j;
        float4 xo = ((float4*)x)[r * 32 + tc];
        float4 o;
        o.x = xo.x + fmaxf((acc[j][0] - m) * rs * gv.x + btv.x, 0.f);
        o.y = xo.y + fmaxf((acc[j][1] - m) * rs * gv.y + btv.y, 0.f);
        o.z = xo.z + fmaxf((acc[j][2] - m) * rs * gv.z + btv.z, 0.f);
        o.w = xo.w + fmaxf((acc[j][3] - m) * rs * gv.w + btv.w, 0.f);
        ((float4*)x)[r * 32 + tc] = o;
    }
}

// ============================ mean pool ====================================
#define PCHUNK 32
__global__ __launch_bounds__(256) void pool_kernel(
    const float* __restrict__ x, const int* __restrict__ batch,
    float* __restrict__ sums, int* __restrict__ cnt)
{
    int wave = (blockIdx.x * 256 + threadIdx.x) >> 6;
    int lane = threadIdx.x & 63;
    int n0 = wave * PCHUNK;
    if (n0 >= NN) return;
    int n1 = n0 + PCHUNK; if (n1 > NN) n1 = NN;

    float2 acc = make_float2(0.f, 0.f);
    int cur = batch[n0];
    int run = 0;
    for (int n = n0; n < n1; ++n) {
        int b = batch[n];
        if (b != cur) {
            float* sp = sums + cur * HID + lane * 2;
            atomicAdd(sp + 0, acc.x);
            atomicAdd(sp + 1, acc.y);
            if (lane == 0) atomicAdd(&cnt[cur], run);
            acc = make_float2(0.f, 0.f);
            run = 0; cur = b;
        }
        float2 v = ((const float2*)x)[(size_t)n * 64 + lane];
        acc.x += v.x; acc.y += v.y; ++run;
    }
    float* sp = sums + cur * HID + lane * 2;
    atomicAdd(sp + 0, acc.x);
    atomicAdd(sp + 1, acc.y);
    if (lane == 0) atomicAdd(&cnt[cur], run);
}

// ============================ head =========================================
__global__ __launch_bounds__(128) void head_kernel(
    const float* __restrict__ sums, const int* __restrict__ cnt,
    const float* __restrict__ pW1, const float* __restrict__ pb1,
    const float* __restrict__ pW2, const float* __restrict__ pb2,
    const float* __restrict__ pg, const float* __restrict__ pbn,
    const float* __restrict__ oW, const float* __restrict__ ob,
    float* __restrict__ out)
{
    __shared__ float s0[128], s1[128], red[4];
    int b = blockIdx.x, c = threadIdx.x;

    float cn = fmaxf((float)cnt[b], 1.f);
    s0[c] = sums[b * HID + c] / cn;
    __syncthreads();

    float a = pb1[c];
#pragma unroll 4
    for (int k = 0; k < HID; ++k) a = fmaf(s0[k], pW1[k * HID + c], a);
    a = fmaxf(a, 0.f);
    s1[c] = a;
    __syncthreads();

    float u = pb2[c];
#pragma unroll 4
    for (int k = 0; k < HID; ++k) u = fmaf(s1[k], pW2[k * HID + c], u);

    float s = u, q = u * u;
#pragma unroll
    for (int off = 1; off < 64; off <<= 1) {
        s += __shfl_xor(s, off, 64);
        q += __shfl_xor(q, off, 64);
    }
    if ((c & 63) == 0) { red[(c >> 6) * 2] = s; red[(c >> 6) * 2 + 1] = q; }
    __syncthreads();
    float S = red[0] + red[2], Q = red[1] + red[3];
    float m = S * (1.f / 128.f);
    float var = Q * (1.f / 128.f) - m * m;
    float rs = rsqrtf(var + 1e-5f);
    float v = fmaxf((u - m) * rs * pg[c] + pbn[c], 0.f);

    float p = v * oW[c];
#pragma unroll
    for (int off = 1; off < 64; off <<= 1) p += __shfl_xor(p, off, 64);
    __syncthreads();
    if ((c & 63) == 0) red[c >> 6] = p;
    __syncthreads();
    if (c == 0) {
        float tot = red[0] + red[1] + ob[0];
        out[b] = 1.f / (1.f + expf(-tot));
    }
}

// ===========================================================================
extern "C" void kernel_launch(void* const* d_in, const int* in_sizes, int n_in,
                              void* d_out, int out_size, void* d_ws, size_t ws_size,
                              hipStream_t stream)
{
    const int*   x_idx    = (const int*)d_in[0];
    const int*   ei       = (const int*)d_in[1];
    const int*   ea       = (const int*)d_in[2];
    const int*   batch    = (const int*)d_in[3];
    const float* node_emb = (const float*)d_in[4];
    const float* e1       = (const float*)d_in[5];
    const float* e2       = (const float*)d_in[6];
    const float* e3       = (const float*)d_in[7];
    const float* W1       = (const float*)d_in[8];
    const float* b1       = (const float*)d_in[9];
    const float* W2       = (const float*)d_in[10];
    const float* b2       = (const float*)d_in[11];
    const float* lg       = (const float*)d_in[12];
    const float* lb       = (const float*)d_in[13];
    const float* pW1      = (const float*)d_in[14];
    const float* pb1      = (const float*)d_in[15];
    const float* pW2      = (const float*)d_in[16];
    const float* pb2      = (const float*)d_in[17];
    const float* pg       = (const float*)d_in[18];
    const float* pbn      = (const float*)d_in[19];
    const float* oW       = (const float*)d_in[20];
    const float* ob       = (const float*)d_in[21];
    float* out = (float*)d_out;

    char* base = (char*)d_ws;
    size_t Sx = (size_t)NN * HID * sizeof(float);           // 51.2 MB
    float* x0   = (float*)(base);
    float* x1   = (float*)(base + Sx);                      // 2nd x buffer / agg
    float* sums = (float*)(base + 2 * Sx);
    int*   cnt  = (int*)  (base + 2 * Sx + BB * HID * 4);
    int*   R    = (int*)  (base + 2 * Sx + BB * HID * 4 + 2048);
    unsigned int* csr = (unsigned int*)((char*)R + 400016);
    int*   aux  = (int*)  ((char*)csr + (size_t)EE * 4);
    unsigned short* wf = (unsigned short*)((char*)aux + 512);
    size_t need = ((char*)wf + (size_t)LL * 2 * 2 * 16384 * 2) - base;

    bool fast = (ws_size >= need);

    embed_kernel<<<(NN * 32 + 255) / 256, 256, 0, stream>>>(x_idx, node_emb, x0);

    if (fast) {
        const int n = NN + 1, NB = (n + 1023) / 1024;
        hipMemsetAsync(R, 0, (size_t)n * sizeof(int), stream);
        hist_kernel <<<(EE + 255) / 256, 256, 0, stream>>>(ei, R);
        scan1_kernel<<<NB, 256, 0, stream>>>(R, aux, n);
        scan2_kernel<<<1, 128, 0, stream>>>(aux, NB);
        scan3_kernel<<<NB - 1, 256, 0, stream>>>(R, aux, n);
        fill_kernel <<<(EE + 255) / 256, 256, 0, stream>>>(ei, ea, R, csr);
        wprep_kernel<<<(LL * 2 * 16384 + 255) / 256, 256, 0, stream>>>(W1, W2, wf);

        for (int l = 0; l < LL; ++l) {
            const float* xin = (l & 1) ? x1 : x0;
            float*       xo  = (l & 1) ? x0 : x1;
            layer_fused_kernel<<<NN / FROWS, 256, 0, stream>>>(
                xin, e1, e2, e3, R, csr, wf + (size_t)l * 65536,
                b1 + l * HID, b2 + l * HID,
                lg + l * HID, lb + l * HID, xo);
        }
        // LL=4 even -> final x in x0
    } else {
        float* x   = x0;
        float* agg = x1;
        for (int l = 0; l < LL; ++l) {
            hipMemsetAsync(agg, 0, Sx, stream);
            edge_kernel<<<(EE * 32 + 255) / 256, 256, 0, stream>>>(
                x, ei, ea, e1, e2, e3, agg);
            gemm_relu_kernel<<<NN / 32, 256, 0, stream>>>(
                x, agg, W1 + l * HID * HID, b1 + l * HID, agg);
            gemm_ln_res_kernel<<<NN / 32, 256, 0, stream>>>(
                agg, W2 + l * HID * HID, b2 + l * HID,
                lg + l * HID, lb + l * HID, x);
        }
    }

    hipMemsetAsync(sums, 0,
                   (size_t)BB * HID * sizeof(float) + BB * sizeof(int), stream);
    {
        int waves = (NN + PCHUNK - 1) / PCHUNK;
        int blocks = (waves + 3) / 4;
        pool_kernel<<<blocks, 256, 0, stream>>>(x0, batch, sums, cnt);
    }
    head_kernel<<<BB, 128, 0, stream>>>(
        sums, cnt, pW1, pb1, pW2, pb2, pg, pbn, oW, ob, out);
}